// Round 17
// baseline (107.946 us; speedup 1.0000x reference)
//
#include <hip/hip_runtime.h>
#include <hip/hip_bf16.h>

#define NT    16384   // B*S tokens
#define DM    1024    // d_model
#define RK    256     // rank
#define N_IN  16
#define N_OUT 16
#define KHH   8
#define MAXTOK 1280   // mu=1024, sigma~31 -> +8 sigma
#define BM    64
#define TPE   (MAXTOK / BM)   // 20 M-tiles per expert
#define KC    4               // K-split chunks (256 each)
#define IN_BLKS  (8 * TPE * 16)         // 2560 (e x kc x cb x tile)
#define OUT_BLKS (8 * TPE * 16)         // 2560
#define TWOUT_BLKS (16 * 64)            // 1024

typedef short bf16x8 __attribute__((ext_vector_type(8)));
typedef float f32x4 __attribute__((ext_vector_type(4)));
typedef unsigned short u16;
typedef u16 u16x8 __attribute__((ext_vector_type(8)));
typedef u16 u16x4 __attribute__((ext_vector_type(4)));

__device__ __forceinline__ u16 f2bf(float f) {
  __hip_bfloat16 b = __float2bfloat16(f);   // RNE, HW cvt
  return *reinterpret_cast<u16*>(&b);
}
__device__ __forceinline__ float bf2f(u16 u) {
  return __uint_as_float((unsigned)u << 16);
}

__device__ __forceinline__ void gl_lds16(const void* g, void* lds) {
  __builtin_amdgcn_global_load_lds(
      (const __attribute__((address_space(1))) void*)g,
      (__attribute__((address_space(3))) void*)lds, 16, 0, 0);
}

// ---------------------------------------------------------------------------
// Transpose tile: src [E][R][C] f32 -> dst [E][C][R] bf16 (flat layout).
// ---------------------------------------------------------------------------
__device__ __forceinline__ void transpose_tile(
    const float* __restrict__ src, u16* __restrict__ dst,
    int R, int C, int e, int tile, float (*ls)[65], int t) {
  const int tilesC = C >> 6;
  const int tr = (tile / tilesC) << 6;
  const int tc = (tile % tilesC) << 6;
  const int row = t >> 2, q = t & 3;
  const float* s = src + (size_t)e * R * C + (size_t)(tr + row) * C + tc + q * 16;
#pragma unroll
  for (int j = 0; j < 4; j++) {
    const float4 v = ((const float4*)s)[j];
    ls[row][q * 16 + j * 4 + 0] = v.x;
    ls[row][q * 16 + j * 4 + 1] = v.y;
    ls[row][q * 16 + j * 4 + 2] = v.z;
    ls[row][q * 16 + j * 4 + 3] = v.w;
  }
  __syncthreads();
  const int cc = t >> 2;
  u16x8 o0, o1;
#pragma unroll
  for (int j = 0; j < 8; j++) o0[j] = f2bf(ls[q * 16 + j][cc]);
#pragma unroll
  for (int j = 0; j < 8; j++) o1[j] = f2bf(ls[q * 16 + 8 + j][cc]);
  u16* d = dst + (size_t)e * C * R + (size_t)(tc + cc) * R + tr + q * 16;
  ((u16x8*)d)[0] = o0;
  ((u16x8*)d)[1] = o1;
}

// ---------------------------------------------------------------------------
// Kernel 1a: blocks 0..31 token lists; 32 pn norms;
// 33..1056: Win transpose -> KC-blocked [E][KC][RK][256] (512B rows).
// ---------------------------------------------------------------------------
__global__ __launch_bounds__(256) void lists_pn_winT(
    const int* __restrict__ in_idx, const int* __restrict__ out_idx,
    const float* __restrict__ pn, const float* __restrict__ Win,
    int* __restrict__ list_in, int* __restrict__ cnt_in,
    int* __restrict__ list_out, int* __restrict__ cnt_out,
    float* __restrict__ pnorm2, u16* __restrict__ WinT) {
  const int b = blockIdx.x;
  const int tid = threadIdx.x, lane = tid & 63, wid = tid >> 6;
  __shared__ float ls[64][65];
  __shared__ int wsum[4];

  if (b >= 33) {  // Win transpose -> blocked [E][KC][RK][256]
    const int b2 = b - 33;
    const int e = b2 >> 6, tile = b2 & 63;
    const int tilesC = RK >> 6;
    const int tr = (tile / tilesC) << 6;   // DM base
    const int tc = (tile % tilesC) << 6;   // RK base
    const int row = tid >> 2, q = tid & 3;
    const float* s = Win + (size_t)e * DM * RK + (size_t)(tr + row) * RK + tc + q * 16;
#pragma unroll
    for (int j = 0; j < 4; j++) {
      const float4 v = ((const float4*)s)[j];
      ls[row][q * 16 + j * 4 + 0] = v.x;
      ls[row][q * 16 + j * 4 + 1] = v.y;
      ls[row][q * 16 + j * 4 + 2] = v.z;
      ls[row][q * 16 + j * 4 + 3] = v.w;
    }
    __syncthreads();
    const int cc = tid >> 2;
    u16x8 o0, o1;
#pragma unroll
    for (int j = 0; j < 8; j++) o0[j] = f2bf(ls[q * 16 + j][cc]);
#pragma unroll
    for (int j = 0; j < 8; j++) o1[j] = f2bf(ls[q * 16 + 8 + j][cc]);
    const int D = tr + q * 16;
    const int kc = D >> 8, dk = D & 255;
    u16* d = WinT + ((size_t)(e * KC + kc) * RK + (tc + cc)) * 256 + dk;
    ((u16x8*)d)[0] = o0;
    ((u16x8*)d)[1] = o1;
    return;
  }
  if (b == 32) {  // pn row norms
    const int p = tid >> 2, q = tid & 3;
    const float* row = pn + (size_t)p * RK + q * 64;
    float s = 0.f;
#pragma unroll
    for (int i = 0; i < 16; i++) {
      const float4 v = ((const float4*)row)[i];
      s += v.x * v.x + v.y * v.y + v.z * v.z + v.w * v.w;
    }
    s += __shfl_xor(s, 1);
    s += __shfl_xor(s, 2);
    if (q == 0) pnorm2[p] = s + 1e-8f;
    return;
  }

  const int e = b & 15, which = b >> 4;
  const int* __restrict__ idx = which ? out_idx : in_idx;
  int* __restrict__ list = (which ? list_out : list_in) + (size_t)e * NT;
  int* __restrict__ cnt = (which ? cnt_out : cnt_in) + e;

  const unsigned long long lt = (1ull << lane) - 1ull;
  int off = 0;
  for (int base = 0; base < NT; base += 1024) {
    const int4 iv = ((const int4*)(idx + base))[tid];
    const bool f0 = iv.x == e, f1 = iv.y == e, f2 = iv.z == e, f3 = iv.w == e;
    const unsigned long long m0 = __ballot(f0), m1 = __ballot(f1),
                             m2 = __ballot(f2), m3 = __ballot(f3);
    const int below = __popcll(m0 & lt) + __popcll(m1 & lt) +
                      __popcll(m2 & lt) + __popcll(m3 & lt);
    const int wtot = __popcll(m0) + __popcll(m1) + __popcll(m2) + __popcll(m3);
    if (lane == 0) wsum[wid] = wtot;
    __syncthreads();
    int b0 = 0, tot = 0;
#pragma unroll
    for (int w = 0; w < 4; w++) { if (w < wid) b0 += wsum[w]; tot += wsum[w]; }
    int pos = off + b0 + below;
    const int t = base + tid * 4;
    if (f0) list[pos++] = t;
    if (f1) list[pos++] = t + 1;
    if (f2) list[pos++] = t + 2;
    if (f3) list[pos++] = t + 3;
    off += tot;
    __syncthreads();
  }
  if (tid == 0) *cnt = off;
}

// ---------------------------------------------------------------------------
// Kernel 1b: gather x rows in IN-expert list order, cvt to bf16, write
// xg[e][kc][slot][256] (KC-blocked, 512B rows). Block = (e, 16 slots).
// Thread: row = tid>>4 (16 rows), 64-col chunk = (tid&15)*64 (one kc).
// ---------------------------------------------------------------------------
__global__ __launch_bounds__(256) void gather_cvt(
    const float* __restrict__ x, const int* __restrict__ list_in,
    const int* __restrict__ cnt_in, u16* __restrict__ xg) {
  const int bid = blockIdx.x;
  const int e = bid / (MAXTOK / 16);
  const int sg = bid % (MAXTOK / 16);
  const int tid = threadIdx.x;
  const int row = tid >> 4;
  const int slot = sg * 16 + row;
  if (slot >= cnt_in[e]) return;
  const int tok = list_in[(size_t)e * NT + slot];
  const int c0 = (tid & 15) * 64;
  const int kc = c0 >> 8, dk = c0 & 255;
  const float* xp = x + (size_t)tok * DM + c0;
  u16* dst = xg + ((size_t)(e * KC + kc) * MAXTOK + slot) * 256 + dk;
#pragma unroll
  for (int i = 0; i < 8; ++i) {
    const float4 a = ((const float4*)xp)[2 * i];
    const float4 c = ((const float4*)xp)[2 * i + 1];
    u16x8 o;
    o[0] = f2bf(a.x); o[1] = f2bf(a.y); o[2] = f2bf(a.z); o[3] = f2bf(a.w);
    o[4] = f2bf(c.x); o[5] = f2bf(c.y); o[6] = f2bf(c.z); o[7] = f2bf(c.w);
    ((u16x8*)dst)[i] = o;
  }
}

// ---------------------------------------------------------------------------
// Kernel 2: blocks 0..2559: input GEMM, BN=128, K-split x4, A SEQUENTIAL by
//   slot from xg (no gather, no toks). h4 stored slot-indexed.
// blocks 2560..: Wout transpose (flat [E][DM][RK], 512B rows).
// ---------------------------------------------------------------------------
__global__ __launch_bounds__(256, 6) void input_gemm_woT(
    const u16* __restrict__ xg, const u16* __restrict__ WinT,
    const int* __restrict__ cnt_in, u16* __restrict__ h4,
    const float* __restrict__ Wout, u16* __restrict__ WoT) {
  __shared__ __align__(16) char smem[24832];
  const int tid = threadIdx.x, lane = tid & 63, w = tid >> 6;
  const int bid = blockIdx.x;

  if (bid >= IN_BLKS) {  // Wout transpose tiles
    const int b2 = bid - IN_BLKS;
    transpose_tile(Wout, WoT, RK, DM, b2 >> 6, b2 & 63,
                   (float(*)[65])smem, tid);
    return;
  }

  const int xcd = bid & 7;
  int j = bid >> 3;                    // 0..(TPE*16-1)
  const int tile = j % TPE;
  j /= TPE;                            // 0..15
  const int cb = j & 1;
  const int e = xcd * 2 + ((j >> 1) & 1);
  const int kc = j >> 2;               // 0..3
  const int t0 = tile * BM;
  if (t0 >= cnt_in[e]) return;

  u16* As = (u16*)smem;                 // 8 KB
  u16* Bs = (u16*)(smem + 8192);        // 16 KB

  const int sub = lane >> 3;
  const int swz8 = ((lane & 7) ^ sub) * 8;
  // B: blocked WinT [e][kc][rows cb*128..+128][256], 512 B row stride
  const u16* Wbase = WinT + ((size_t)(e * KC + kc) * RK + cb * 128) * 256;
  // A: sequential slots from xg
  const int ar0 = (w * 2 + 0) * 8 + sub;
  const int ar1 = (w * 2 + 1) * 8 + sub;
  const u16* xgbase = xg + (size_t)(e * KC + kc) * MAXTOK * 256;
  const u16* asrc0 = xgbase + (size_t)(t0 + ar0) * 256 + swz8;
  const u16* asrc1 = xgbase + (size_t)(t0 + ar1) * 256 + swz8;

  f32x4 acc[4][2];
#pragma unroll
  for (int m = 0; m < 4; m++)
#pragma unroll
    for (int jx = 0; jx < 2; jx++) acc[m][jx] = (f32x4)0.f;

  const int l15 = lane & 15, lg = lane >> 4;

#pragma unroll
  for (int it = 0; it < 4; ++it) {
    const int k0 = it * 64;
    if (it) __syncthreads();
    gl_lds16(asrc0 + k0, As + (w * 2 + 0) * 512);
    gl_lds16(asrc1 + k0, As + (w * 2 + 1) * 512);
#pragma unroll
    for (int i = 0; i < 4; ++i) {       // 128 B rows / 8 per instr / 4 waves
      const int g = w * 4 + i;
      const int n = g * 8 + sub;
      gl_lds16(Wbase + (size_t)n * 256 + k0 + swz8, Bs + g * 512);
    }
    __syncthreads();
#pragma unroll
    for (int kk = 0; kk < 2; ++kk) {
      const int sw = (((kk * 4 + lg) ^ (l15 & 7)) << 4);
      bf16x8 fa[4];
#pragma unroll
      for (int m = 0; m < 4; ++m)
        fa[m] = *(const bf16x8*)((const char*)As + (m * 16 + l15) * 128 + sw);
#pragma unroll
      for (int jx = 0; jx < 2; ++jx) {
        const int n = w * 32 + jx * 16 + l15;
        const bf16x8 fb = *(const bf16x8*)((const char*)Bs + n * 128 + sw);
#pragma unroll
        for (int m = 0; m < 4; ++m)
          acc[m][jx] = __builtin_amdgcn_mfma_f32_16x16x32_bf16(fa[m], fb, acc[m][jx], 0, 0, 0);
      }
    }
  }

  // store bf16 partial, slot-indexed (pad slots harmless; K3 guards)
  u16* hp4 = h4 + ((size_t)(kc * N_IN + e) * MAXTOK + t0) * 256 + cb * 128;
#pragma unroll
  for (int m = 0; m < 4; ++m)
#pragma unroll
    for (int r = 0; r < 4; ++r) {
      const int slot = m * 16 + lg * 4 + r;
      u16* hp = hp4 + (size_t)slot * 256 + w * 32 + l15;
#pragma unroll
      for (int jx = 0; jx < 2; ++jx) hp[jx * 16] = f2bf(acc[m][jx][r]);
    }
}

// ---------------------------------------------------------------------------
// Kernel 3: partial-sum + 8 Householder reflections. Slot-indexed input,
// token-indexed output. One wave per slot.
// ---------------------------------------------------------------------------
__global__ __launch_bounds__(256) void hh_k(
    const u16* __restrict__ h4, u16* __restrict__ hb,
    const float* __restrict__ pn, const float* __restrict__ pnorm2,
    const int* __restrict__ pidx, const int* __restrict__ list_in,
    const int* __restrict__ cnt_in) {
  const int bid = blockIdx.x;
  const int e = bid / (MAXTOK / 4);
  const int sg = bid % (MAXTOK / 4);
  const int lane = threadIdx.x & 63;
  const int slot = sg * 4 + (threadIdx.x >> 6);
  if (slot >= cnt_in[e]) return;
  const int t = list_in[(size_t)e * NT + slot];

  float4 hv;
  {
    const size_t base = (size_t)e * MAXTOK + slot;
    const u16x4 p0 = ((const u16x4*)(h4 + ((size_t)(0 * N_IN) * MAXTOK + base) * 256))[lane];
    const u16x4 p1 = ((const u16x4*)(h4 + ((size_t)(1 * N_IN) * MAXTOK + base) * 256))[lane];
    const u16x4 p2 = ((const u16x4*)(h4 + ((size_t)(2 * N_IN) * MAXTOK + base) * 256))[lane];
    const u16x4 p3 = ((const u16x4*)(h4 + ((size_t)(3 * N_IN) * MAXTOK + base) * 256))[lane];
    hv.x = (bf2f(p0[0]) + bf2f(p1[0])) + (bf2f(p2[0]) + bf2f(p3[0]));
    hv.y = (bf2f(p0[1]) + bf2f(p1[1])) + (bf2f(p2[1]) + bf2f(p3[1]));
    hv.z = (bf2f(p0[2]) + bf2f(p1[2])) + (bf2f(p2[2]) + bf2f(p3[2]));
    hv.w = (bf2f(p0[3]) + bf2f(p1[3])) + (bf2f(p2[3]) + bf2f(p3[3]));
  }

#pragma unroll
  for (int k = 0; k < KHH; k++) {
    const int p = pidx[t * KHH + k];
    const float4 v = ((const float4*)(pn + (size_t)p * RK))[lane];
    float dvh = v.x * hv.x + v.y * hv.y + v.z * hv.z + v.w * hv.w;
#pragma unroll
    for (int s = 32; s; s >>= 1) dvh += __shfl_xor(dvh, s);
    const float c = 2.f * dvh / pnorm2[p];
    hv.x = fmaf(-c, v.x, hv.x);
    hv.y = fmaf(-c, v.y, hv.y);
    hv.z = fmaf(-c, v.z, hv.z);
    hv.w = fmaf(-c, v.w, hv.w);
  }
  u16x4 o;
  o[0] = f2bf(hv.x); o[1] = f2bf(hv.y); o[2] = f2bf(hv.z); o[3] = f2bf(hv.w);
  ((u16x4*)(hb + (size_t)t * RK))[lane] = o;
}

// ---------------------------------------------------------------------------
// Kernel 4: output GEMM (BM=64, BN=128), XCD-pinned, 2-phase LDS (4 iters).
// A gathered from token-indexed hb via list_out; out stores via toks.
// ---------------------------------------------------------------------------
__global__ __launch_bounds__(256, 6) void output_gemm_mfma(
    const u16* __restrict__ hb, const u16* __restrict__ WoT,
    const int* __restrict__ list, const int* __restrict__ cnt,
    float* __restrict__ out) {
  const int bid = blockIdx.x;
  const int xcd = bid & 7;
  int j = bid >> 3;                    // 0..(TPE*16-1)
  const int tile = j % TPE;
  j /= TPE;                            // 0..15
  const int e = xcd * 2 + (j & 1);
  const int cb = j >> 1;               // 0..7
  const int nt = cnt[e];
  const int t0 = tile * BM;
  if (t0 >= nt) return;
  const int* __restrict__ lst = list + (size_t)e * NT + t0;
  const int ntok = min(BM, nt - t0);

  __shared__ __align__(16) u16 As[BM * 64];    // 8 KB
  __shared__ __align__(16) u16 Bs[128 * 64];   // 16 KB
  __shared__ int toks[BM];

  const int tid = threadIdx.x, lane = tid & 63, w = tid >> 6;
  if (tid < BM) toks[tid] = lst[tid < ntok ? tid : 0];
  __syncthreads();

  const int sub = lane >> 3;
  const int swz8 = ((lane & 7) ^ sub) * 8;
  const u16* Wbase = WoT + (size_t)e * DM * RK + (size_t)(cb * 128) * RK;
  const int ar0 = (w * 2 + 0) * 8 + sub;
  const int ar1 = (w * 2 + 1) * 8 + sub;
  const u16* asrc0 = hb + (size_t)toks[ar0] * RK + swz8;
  const u16* asrc1 = hb + (size_t)toks[ar1] * RK + swz8;

  f32x4 acc[4][2];
#pragma unroll
  for (int m = 0; m < 4; m++)
#pragma unroll
    for (int jx = 0; jx < 2; jx++) acc[m][jx] = (f32x4)0.f;

  const int l15 = lane & 15, lg = lane >> 4;

#pragma unroll
  for (int it = 0; it < RK / 64; ++it) {
    const int k0 = it * 64;
    if (it) __syncthreads();
    gl_lds16(asrc0 + k0, As + (w * 2 + 0) * 512);
    gl_lds16(asrc1 + k0, As + (w * 2 + 1) * 512);
#pragma unroll
    for (int i = 0; i < 4; ++i) {
      const int g = w * 4 + i;
      const int n = g * 8 + sub;
      gl_lds16(Wbase + (size_t)n * RK + k0 + swz8, Bs + g * 512);
    }
    __syncthreads();
#pragma unroll
    for (int kk = 0; kk < 2; ++kk) {
      const int sw = (((kk * 4 + lg) ^ (l15 & 7)) << 4);
      bf16x8 fa[4];
#pragma unroll
      for (int m = 0; m < 4; ++m)
        fa[m] = *(const bf16x8*)((const char*)As + (m * 16 + l15) * 128 + sw);
#pragma unroll
      for (int jx = 0; jx < 2; ++jx) {
        const int n = w * 32 + jx * 16 + l15;
        const bf16x8 fb = *(const bf16x8*)((const char*)Bs + n * 128 + sw);
#pragma unroll
        for (int m = 0; m < 4; ++m)
          acc[m][jx] = __builtin_amdgcn_mfma_f32_16x16x32_bf16(fa[m], fb, acc[m][jx], 0, 0, 0);
      }
    }
  }

#pragma unroll
  for (int m = 0; m < 4; ++m)
#pragma unroll
    for (int r = 0; r < 4; ++r) {
      const int slot = m * 16 + lg * 4 + r;
      if (slot < ntok) {
        float* op = out + (size_t)toks[slot] * DM + cb * 128 + w * 32 + l15;
#pragma unroll
        for (int jx = 0; jx < 2; ++jx) op[jx * 16] = acc[m][jx][r];
      }
    }
}

// ---------------------------------------------------------------------------
extern "C" void kernel_launch(void* const* d_in, const int* in_sizes, int n_in,
                              void* d_out, int out_size, void* d_ws,
                              size_t ws_size, hipStream_t stream) {
  const float* x     = (const float*)d_in[0];
  const float* Win   = (const float*)d_in[1];
  const float* pn    = (const float*)d_in[2];
  const float* Wout  = (const float*)d_in[3];
  const int* in_idx  = (const int*)d_in[4];
  const int* pidx    = (const int*)d_in[5];
  const int* out_idx = (const int*)d_in[6];
  float* out = (float*)d_out;

  char* ws = (char*)d_ws;
  u16* WinT  = (u16*)ws;                    ws += (size_t)N_IN * RK * DM * 2;     // 8.4 MB
  u16* WoT   = (u16*)ws;                    ws += (size_t)N_OUT * DM * RK * 2;    // 8.4 MB
  u16* xg    = (u16*)ws;                    ws += (size_t)N_IN * KC * MAXTOK * 256 * 2;  // 41.9 MB
  u16* h4    = (u16*)ws;                    ws += (size_t)KC * N_IN * MAXTOK * 256 * 2;  // 41.9 MB
  u16* hb    = (u16*)ws;                    ws += (size_t)NT * RK * 2;            // 8.4 MB
  int* list_in  = (int*)ws;                 ws += (size_t)N_IN * NT * 4;
  int* list_out = (int*)ws;                 ws += (size_t)N_OUT * NT * 4;
  int* cnt_in   = (int*)ws;                 ws += 64;
  int* cnt_out  = (int*)ws;                 ws += 64;
  float* pnorm2 = (float*)ws;

  hipLaunchKernelGGL(lists_pn_winT, dim3(33 + 1024), dim3(256), 0, stream,
                     in_idx, out_idx, pn, Win, list_in, cnt_in,
                     list_out, cnt_out, pnorm2, WinT);
  hipLaunchKernelGGL(gather_cvt, dim3(N_IN * (MAXTOK / 16)), dim3(256), 0,
                     stream, x, list_in, cnt_in, xg);
  hipLaunchKernelGGL(input_gemm_woT, dim3(IN_BLKS + TWOUT_BLKS), dim3(256),
                     0, stream, xg, WinT, cnt_in, h4, Wout, WoT);
  hipLaunchKernelGGL(hh_k, dim3(N_IN * (MAXTOK / 4)), dim3(256), 0, stream,
                     h4, hb, pn, pnorm2, pidx, list_in, cnt_in);
  hipLaunchKernelGGL(output_gemm_mfma, dim3(OUT_BLKS), dim3(256), 0, stream,
                     hb, WoT, list_out, cnt_out, out);
}

// Round 18
// 80.706 us; speedup vs baseline: 1.3375x; 1.3375x over previous
//
#include <hip/hip_runtime.h>
#include <hip/hip_bf16.h>

#define NT    16384   // B*S tokens
#define DM    1024    // d_model
#define RK    256     // rank
#define N_IN  16
#define N_OUT 16
#define KHH   8
#define MAXTOK 1536
#define BM    64
#define TPE   (MAXTOK / BM)   // 24 M-tiles per expert
#define KC    4               // K-split chunks (256 each)
#define IN_BLKS  (8 * TPE * 8)          // 1536 (BN=256)
#define OUT_BLKS (8 * TPE * 16)         // 3072
#define TWOUT_BLKS (16 * 64)            // 1024

typedef short bf16x8 __attribute__((ext_vector_type(8)));
typedef float f32x4 __attribute__((ext_vector_type(4)));
typedef unsigned short u16;
typedef u16 u16x8 __attribute__((ext_vector_type(8)));
typedef u16 u16x4 __attribute__((ext_vector_type(4)));

__device__ __forceinline__ u16 f2bf(float f) {
  __hip_bfloat16 b = __float2bfloat16(f);   // RNE, HW cvt
  return *reinterpret_cast<u16*>(&b);
}
__device__ __forceinline__ float bf2f(u16 u) {
  return __uint_as_float((unsigned)u << 16);
}

__device__ __forceinline__ void gl_lds16(const void* g, void* lds) {
  __builtin_amdgcn_global_load_lds(
      (const __attribute__((address_space(1))) void*)g,
      (__attribute__((address_space(3))) void*)lds, 16, 0, 0);
}

// ---------------------------------------------------------------------------
// Transpose tile: src [E][R][C] f32 -> dst [E][C][R] bf16 (flat layout).
// ls points at >=64*65*4 B of LDS.
// ---------------------------------------------------------------------------
__device__ __forceinline__ void transpose_tile(
    const float* __restrict__ src, u16* __restrict__ dst,
    int R, int C, int e, int tile, float (*ls)[65], int t) {
  const int tilesC = C >> 6;
  const int tr = (tile / tilesC) << 6;
  const int tc = (tile % tilesC) << 6;
  const int row = t >> 2, q = t & 3;
  const float* s = src + (size_t)e * R * C + (size_t)(tr + row) * C + tc + q * 16;
#pragma unroll
  for (int j = 0; j < 4; j++) {
    const float4 v = ((const float4*)s)[j];
    ls[row][q * 16 + j * 4 + 0] = v.x;
    ls[row][q * 16 + j * 4 + 1] = v.y;
    ls[row][q * 16 + j * 4 + 2] = v.z;
    ls[row][q * 16 + j * 4 + 3] = v.w;
  }
  __syncthreads();
  const int cc = t >> 2;
  u16x8 o0, o1;
#pragma unroll
  for (int j = 0; j < 8; j++) o0[j] = f2bf(ls[q * 16 + j][cc]);
#pragma unroll
  for (int j = 0; j < 8; j++) o1[j] = f2bf(ls[q * 16 + 8 + j][cc]);
  u16* d = dst + (size_t)e * C * R + (size_t)(tc + cc) * R + tr + q * 16;
  ((u16x8*)d)[0] = o0;
  ((u16x8*)d)[1] = o1;
}

// ---------------------------------------------------------------------------
// Kernel 1: blocks 0..31 token lists; 32 pn norms;
// 33..1056: Win transpose -> KC-blocked [E][KC][RK][256] (512B rows).
// ---------------------------------------------------------------------------
__global__ __launch_bounds__(256) void lists_pn_winT(
    const int* __restrict__ in_idx, const int* __restrict__ out_idx,
    const float* __restrict__ pn, const float* __restrict__ Win,
    int* __restrict__ list_in, int* __restrict__ cnt_in,
    int* __restrict__ list_out, int* __restrict__ cnt_out,
    float* __restrict__ pnorm2, u16* __restrict__ WinT) {
  const int b = blockIdx.x;
  const int tid = threadIdx.x, lane = tid & 63, wid = tid >> 6;
  __shared__ float ls[64][65];
  __shared__ int wsum[4];

  if (b >= 33) {  // Win transpose -> blocked [E][KC][RK][256]
    const int b2 = b - 33;
    const int e = b2 >> 6, tile = b2 & 63;
    const int tilesC = RK >> 6;
    const int tr = (tile / tilesC) << 6;   // DM base
    const int tc = (tile % tilesC) << 6;   // RK base
    const int row = tid >> 2, q = tid & 3;
    const float* s = Win + (size_t)e * DM * RK + (size_t)(tr + row) * RK + tc + q * 16;
#pragma unroll
    for (int j = 0; j < 4; j++) {
      const float4 v = ((const float4*)s)[j];
      ls[row][q * 16 + j * 4 + 0] = v.x;
      ls[row][q * 16 + j * 4 + 1] = v.y;
      ls[row][q * 16 + j * 4 + 2] = v.z;
      ls[row][q * 16 + j * 4 + 3] = v.w;
    }
    __syncthreads();
    const int cc = tid >> 2;
    u16x8 o0, o1;
#pragma unroll
    for (int j = 0; j < 8; j++) o0[j] = f2bf(ls[q * 16 + j][cc]);
#pragma unroll
    for (int j = 0; j < 8; j++) o1[j] = f2bf(ls[q * 16 + 8 + j][cc]);
    const int D = tr + q * 16;
    const int kc = D >> 8, dk = D & 255;
    u16* d = WinT + ((size_t)(e * KC + kc) * RK + (tc + cc)) * 256 + dk;
    ((u16x8*)d)[0] = o0;
    ((u16x8*)d)[1] = o1;
    return;
  }
  if (b == 32) {  // pn row norms
    const int p = tid >> 2, q = tid & 3;
    const float* row = pn + (size_t)p * RK + q * 64;
    float s = 0.f;
#pragma unroll
    for (int i = 0; i < 16; i++) {
      const float4 v = ((const float4*)row)[i];
      s += v.x * v.x + v.y * v.y + v.z * v.z + v.w * v.w;
    }
    s += __shfl_xor(s, 1);
    s += __shfl_xor(s, 2);
    if (q == 0) pnorm2[p] = s + 1e-8f;
    return;
  }

  const int e = b & 15, which = b >> 4;
  const int* __restrict__ idx = which ? out_idx : in_idx;
  int* __restrict__ list = (which ? list_out : list_in) + (size_t)e * NT;
  int* __restrict__ cnt = (which ? cnt_out : cnt_in) + e;

  const unsigned long long lt = (1ull << lane) - 1ull;
  int off = 0;
  for (int base = 0; base < NT; base += 1024) {
    const int4 iv = ((const int4*)(idx + base))[tid];
    const bool f0 = iv.x == e, f1 = iv.y == e, f2 = iv.z == e, f3 = iv.w == e;
    const unsigned long long m0 = __ballot(f0), m1 = __ballot(f1),
                             m2 = __ballot(f2), m3 = __ballot(f3);
    const int below = __popcll(m0 & lt) + __popcll(m1 & lt) +
                      __popcll(m2 & lt) + __popcll(m3 & lt);
    const int wtot = __popcll(m0) + __popcll(m1) + __popcll(m2) + __popcll(m3);
    if (lane == 0) wsum[wid] = wtot;
    __syncthreads();
    int b0 = 0, tot = 0;
#pragma unroll
    for (int w = 0; w < 4; w++) { if (w < wid) b0 += wsum[w]; tot += wsum[w]; }
    int pos = off + b0 + below;
    const int t = base + tid * 4;
    if (f0) list[pos++] = t;
    if (f1) list[pos++] = t + 1;
    if (f2) list[pos++] = t + 2;
    if (f3) list[pos++] = t + 3;
    off += tot;
    __syncthreads();
  }
  if (tid == 0) *cnt = off;
}

// ---------------------------------------------------------------------------
// Kernel 2: blocks 0..1535: input GEMM, BN=256, K-split x4.
//   A staged as RAW F32 via global_load_lds (DMA-only staging, slot-XOR
//   swizzled source); f32->bf16 cvt happens at fragment-read time, where it
//   overlaps MFMA. B from blocked WinT (512B rows). No xb buffer.
// blocks 1536..: Wout transpose.
// ---------------------------------------------------------------------------
__global__ __launch_bounds__(256, 3) void input_gemm_woT(
    const float* __restrict__ x, const u16* __restrict__ WinT,
    const int* __restrict__ list, const int* __restrict__ cnt,
    u16* __restrict__ h4,
    const float* __restrict__ Wout, u16* __restrict__ WoT) {
  __shared__ __align__(16) char smem[49920];  // Af32 16K | Bs 32K | toks
  const int tid = threadIdx.x, lane = tid & 63, w = tid >> 6;
  const int bid = blockIdx.x;

  if (bid >= IN_BLKS) {  // Wout transpose tiles
    const int b2 = bid - IN_BLKS;
    transpose_tile(Wout, WoT, RK, DM, b2 >> 6, b2 & 63,
                   (float(*)[65])smem, tid);
    return;
  }

  const int xcd = bid & 7;
  int j = bid >> 3;                    // 0..(TPE*8-1)
  const int tile = j % TPE;
  j /= TPE;                            // 0..7
  const int e = xcd * 2 + (j & 1);
  const int kc = j >> 1;               // 0..3
  const int nt = cnt[e];
  const int t0 = tile * BM;
  if (t0 >= nt) return;
  const int* __restrict__ lst = list + (size_t)e * NT + t0;
  const int ntok = min(BM, nt - t0);

  float* Af = (float*)smem;             // [64 rows][16 phys slots x 16B] f32
  u16* Bs = (u16*)(smem + 16384);       // 32 KB
  int* toks = (int*)(smem + 16384 + 32768);

  if (tid < BM) toks[tid] = lst[tid < ntok ? tid : 0];
  __syncthreads();

  // ---- A staging map (gl_lds, f32): 16 instrs, 4/wave. Instr g covers rows
  // g*4 + (lane>>4); lane's 16B slot ps = lane&15; source logical slot
  // s = ps ^ (row&15) (involution; read side applies same XOR).
  const int ps = lane & 15;
  const int r4 = lane >> 4;
  const float* asrc[4];
#pragma unroll
  for (int i = 0; i < 4; ++i) {
    const int g = w * 4 + i;
    const int row = g * 4 + r4;
    asrc[i] = x + (size_t)toks[row] * DM + kc * 256 + ((ps ^ (row & 15)) << 2);
  }

  // ---- B staging map: blocked WinT [e][kc][256 rows][256], 512B rows
  const int sub = lane >> 3;
  const int swz8 = ((lane & 7) ^ sub) * 8;
  const u16* Wbase = WinT + (size_t)(e * KC + kc) * RK * 256;

  f32x4 acc[4][4];
#pragma unroll
  for (int m = 0; m < 4; m++)
#pragma unroll
    for (int jx = 0; jx < 4; jx++) acc[m][jx] = (f32x4)0.f;

  const int l15 = lane & 15, lg = lane >> 4;

#pragma unroll
  for (int it = 0; it < 4; ++it) {
    const int k0 = it * 64;
    if (it) __syncthreads();
    // A: f32 DMA (4/wave)
#pragma unroll
    for (int i = 0; i < 4; ++i)
      gl_lds16(asrc[i] + k0, Af + (w * 4 + i) * 256);
    // B: bf16 DMA (8/wave)
#pragma unroll
    for (int i = 0; i < 8; ++i) {
      const int g = w * 8 + i;
      const int n = g * 8 + sub;
      gl_lds16(Wbase + (size_t)n * 256 + k0 + swz8, Bs + g * 512);
    }
    __syncthreads();
#pragma unroll
    for (int kk = 0; kk < 2; ++kk) {
      // A fragment: f32 slots s0,s0+1 (phys ^ l15), cvt to bf16 here
      const int s0 = kk * 8 + lg * 2;
      const int p0 = s0 ^ l15;
      const int p1 = (s0 + 1) ^ l15;
      bf16x8 fa[4];
#pragma unroll
      for (int m = 0; m < 4; ++m) {
        const char* rowb = (const char*)Af + (m * 16 + l15) * 256;
        const float4 lo = *(const float4*)(rowb + p0 * 16);
        const float4 hi = *(const float4*)(rowb + p1 * 16);
        u16x8 t;
        t[0] = f2bf(lo.x); t[1] = f2bf(lo.y); t[2] = f2bf(lo.z); t[3] = f2bf(lo.w);
        t[4] = f2bf(hi.x); t[5] = f2bf(hi.y); t[6] = f2bf(hi.z); t[7] = f2bf(hi.w);
        fa[m] = *(bf16x8*)&t;
      }
      const int sw = (((kk * 4 + lg) ^ (l15 & 7)) << 4);
#pragma unroll
      for (int jx = 0; jx < 4; ++jx) {
        const int n = w * 64 + jx * 16 + l15;
        const bf16x8 fb = *(const bf16x8*)((const char*)Bs + n * 128 + sw);
#pragma unroll
        for (int m = 0; m < 4; ++m)
          acc[m][jx] = __builtin_amdgcn_mfma_f32_16x16x32_bf16(fa[m], fb, acc[m][jx], 0, 0, 0);
      }
    }
  }

  // store bf16 partial
  u16* hp4 = h4 + (size_t)kc * NT * RK;
#pragma unroll
  for (int m = 0; m < 4; ++m)
#pragma unroll
    for (int r = 0; r < 4; ++r) {
      const int slot = m * 16 + lg * 4 + r;
      if (slot < ntok) {
        u16* hp = hp4 + (size_t)toks[slot] * RK + w * 64 + l15;
#pragma unroll
        for (int jx = 0; jx < 4; ++jx) hp[jx * 16] = f2bf(acc[m][jx][r]);
      }
    }
}

// ---------------------------------------------------------------------------
// Kernel 3: partial-sum + 8 Householder reflections per token.
// ---------------------------------------------------------------------------
__global__ __launch_bounds__(256) void hh_k(
    const u16* __restrict__ h4, u16* __restrict__ hb,
    const float* __restrict__ pn, const float* __restrict__ pnorm2,
    const int* __restrict__ pidx) {
  const int lane = threadIdx.x & 63;
  const int t = blockIdx.x * 4 + (threadIdx.x >> 6);

  float4 hv;
  {
    const u16x4 p0 = ((const u16x4*)(h4 + ((size_t)0 * NT + t) * RK))[lane];
    const u16x4 p1 = ((const u16x4*)(h4 + ((size_t)1 * NT + t) * RK))[lane];
    const u16x4 p2 = ((const u16x4*)(h4 + ((size_t)2 * NT + t) * RK))[lane];
    const u16x4 p3 = ((const u16x4*)(h4 + ((size_t)3 * NT + t) * RK))[lane];
    hv.x = (bf2f(p0[0]) + bf2f(p1[0])) + (bf2f(p2[0]) + bf2f(p3[0]));
    hv.y = (bf2f(p0[1]) + bf2f(p1[1])) + (bf2f(p2[1]) + bf2f(p3[1]));
    hv.z = (bf2f(p0[2]) + bf2f(p1[2])) + (bf2f(p2[2]) + bf2f(p3[2]));
    hv.w = (bf2f(p0[3]) + bf2f(p1[3])) + (bf2f(p2[3]) + bf2f(p3[3]));
  }

#pragma unroll
  for (int k = 0; k < KHH; k++) {
    const int p = pidx[t * KHH + k];
    const float4 v = ((const float4*)(pn + (size_t)p * RK))[lane];
    float dvh = v.x * hv.x + v.y * hv.y + v.z * hv.z + v.w * hv.w;
#pragma unroll
    for (int s = 32; s; s >>= 1) dvh += __shfl_xor(dvh, s);
    const float c = 2.f * dvh / pnorm2[p];
    hv.x = fmaf(-c, v.x, hv.x);
    hv.y = fmaf(-c, v.y, hv.y);
    hv.z = fmaf(-c, v.z, hv.z);
    hv.w = fmaf(-c, v.w, hv.w);
  }
  u16x4 o;
  o[0] = f2bf(hv.x); o[1] = f2bf(hv.y); o[2] = f2bf(hv.z); o[3] = f2bf(hv.w);
  ((u16x4*)(hb + (size_t)t * RK))[lane] = o;
}

// ---------------------------------------------------------------------------
// Kernel 4: output GEMM (BM=64, BN=128), XCD-pinned, 2-phase LDS (4 iters).
// ---------------------------------------------------------------------------
__global__ __launch_bounds__(256, 6) void output_gemm_mfma(
    const u16* __restrict__ hb, const u16* __restrict__ WoT,
    const int* __restrict__ list, const int* __restrict__ cnt,
    float* __restrict__ out) {
  const int bid = blockIdx.x;
  const int xcd = bid & 7;
  int j = bid >> 3;                    // 0..(TPE*16-1)
  const int tile = j % TPE;
  j /= TPE;                            // 0..15
  const int e = xcd * 2 + (j & 1);
  const int cb = j >> 1;               // 0..7
  const int nt = cnt[e];
  const int t0 = tile * BM;
  if (t0 >= nt) return;
  const int* __restrict__ lst = list + (size_t)e * NT + t0;
  const int ntok = min(BM, nt - t0);

  __shared__ __align__(16) u16 As[BM * 64];    // 8 KB
  __shared__ __align__(16) u16 Bs[128 * 64];   // 16 KB
  __shared__ int toks[BM];

  const int tid = threadIdx.x, lane = tid & 63, w = tid >> 6;
  if (tid < BM) toks[tid] = lst[tid < ntok ? tid : 0];
  __syncthreads();

  const int sub = lane >> 3;
  const int swz8 = ((lane & 7) ^ sub) * 8;
  const u16* Wbase = WoT + (size_t)e * DM * RK + (size_t)(cb * 128) * RK;
  const int ar0 = (w * 2 + 0) * 8 + sub;
  const int ar1 = (w * 2 + 1) * 8 + sub;
  const u16* asrc0 = hb + (size_t)toks[ar0] * RK + swz8;
  const u16* asrc1 = hb + (size_t)toks[ar1] * RK + swz8;

  f32x4 acc[4][2];
#pragma unroll
  for (int m = 0; m < 4; m++)
#pragma unroll
    for (int jx = 0; jx < 2; jx++) acc[m][jx] = (f32x4)0.f;

  const int l15 = lane & 15, lg = lane >> 4;

#pragma unroll
  for (int it = 0; it < RK / 64; ++it) {
    const int k0 = it * 64;
    if (it) __syncthreads();
    gl_lds16(asrc0 + k0, As + (w * 2 + 0) * 512);
    gl_lds16(asrc1 + k0, As + (w * 2 + 1) * 512);
#pragma unroll
    for (int i = 0; i < 4; ++i) {
      const int g = w * 4 + i;
      const int n = g * 8 + sub;
      gl_lds16(Wbase + (size_t)n * RK + k0 + swz8, Bs + g * 512);
    }
    __syncthreads();
#pragma unroll
    for (int kk = 0; kk < 2; ++kk) {
      const int sw = (((kk * 4 + lg) ^ (l15 & 7)) << 4);
      bf16x8 fa[4];
#pragma unroll
      for (int m = 0; m < 4; ++m)
        fa[m] = *(const bf16x8*)((const char*)As + (m * 16 + l15) * 128 + sw);
#pragma unroll
      for (int jx = 0; jx < 2; ++jx) {
        const int n = w * 32 + jx * 16 + l15;
        const bf16x8 fb = *(const bf16x8*)((const char*)Bs + n * 128 + sw);
#pragma unroll
        for (int m = 0; m < 4; ++m)
          acc[m][jx] = __builtin_amdgcn_mfma_f32_16x16x32_bf16(fa[m], fb, acc[m][jx], 0, 0, 0);
      }
    }
  }

#pragma unroll
  for (int m = 0; m < 4; ++m)
#pragma unroll
    for (int r = 0; r < 4; ++r) {
      const int slot = m * 16 + lg * 4 + r;
      if (slot < ntok) {
        float* op = out + (size_t)toks[slot] * DM + cb * 128 + w * 32 + l15;
#pragma unroll
        for (int jx = 0; jx < 2; ++jx) op[jx * 16] = acc[m][jx][r];
      }
    }
}

// ---------------------------------------------------------------------------
extern "C" void kernel_launch(void* const* d_in, const int* in_sizes, int n_in,
                              void* d_out, int out_size, void* d_ws,
                              size_t ws_size, hipStream_t stream) {
  const float* x     = (const float*)d_in[0];
  const float* Win   = (const float*)d_in[1];
  const float* pn    = (const float*)d_in[2];
  const float* Wout  = (const float*)d_in[3];
  const int* in_idx  = (const int*)d_in[4];
  const int* pidx    = (const int*)d_in[5];
  const int* out_idx = (const int*)d_in[6];
  float* out = (float*)d_out;

  char* ws = (char*)d_ws;
  u16* WinT  = (u16*)ws;                    ws += (size_t)N_IN * RK * DM * 2;   // blocked
  u16* WoT   = (u16*)ws;                    ws += (size_t)N_OUT * DM * RK * 2;
  u16* hb    = (u16*)ws;                    ws += (size_t)NT * RK * 2;
  u16* h4    = (u16*)ws;                    ws += (size_t)KC * NT * RK * 2;
  int* list_in  = (int*)ws;                 ws += (size_t)N_IN * NT * 4;
  int* list_out = (int*)ws;                 ws += (size_t)N_OUT * NT * 4;
  int* cnt_in   = (int*)ws;                 ws += 64;
  int* cnt_out  = (int*)ws;                 ws += 64;
  float* pnorm2 = (float*)ws;

  hipLaunchKernelGGL(lists_pn_winT, dim3(33 + 1024), dim3(256), 0, stream,
                     in_idx, out_idx, pn, Win, list_in, cnt_in,
                     list_out, cnt_out, pnorm2, WinT);
  hipLaunchKernelGGL(input_gemm_woT, dim3(IN_BLKS + TWOUT_BLKS), dim3(256),
                     0, stream, x, WinT, list_in, cnt_in, h4, Wout, WoT);
  hipLaunchKernelGGL(hh_k, dim3(NT / 4), dim3(256), 0, stream,
                     h4, hb, pn, pnorm2, pidx);
  hipLaunchKernelGGL(output_gemm_mfma, dim3(OUT_BLKS), dim3(256), 0, stream,
                     hb, WoT, list_out, cnt_out, out);
}